// Round 1
// baseline (2871.813 us; speedup 1.0000x reference)
//
#include <hip/hip_runtime.h>
#include <math.h>

#define B_ 2
#define C_ 64
#define H_ 192
#define W_ 192
#define HW_ (H_*W_)
#define KK_ 9

// ---------------- LayerNorm over channel axis ----------------
__global__ void ln_kernel(const float* __restrict__ x,
                          const float* __restrict__ lnw,
                          const float* __restrict__ lnb,
                          float* __restrict__ xn) {
    int p = blockIdx.x * blockDim.x + threadIdx.x;   // pixel in [0, B*HW)
    if (p >= B_ * HW_) return;
    int b = p / HW_, pix = p % HW_;
    const float* xb = x + (size_t)b * C_ * HW_ + pix;
    float s = 0.f, s2 = 0.f;
    #pragma unroll
    for (int c = 0; c < C_; ++c) {
        float v = xb[(size_t)c * HW_];
        s += v; s2 += v * v;
    }
    float mu  = s * (1.0f / C_);
    float var = s2 * (1.0f / C_) - mu * mu;
    float inv = rsqrtf(var + 1e-5f);
    float* yb = xn + (size_t)b * C_ * HW_ + pix;
    #pragma unroll
    for (int c = 0; c < C_; ++c) {
        yb[(size_t)c * HW_] = (xb[(size_t)c * HW_] - mu) * inv * lnw[c] + lnb[c];
    }
}

// ---------------- offset(18ch) + mask(9ch, sigmoid) 3x3 conv ----------------
__global__ void conv27_kernel(const float* __restrict__ xn,
                              const float* __restrict__ offw, const float* __restrict__ offb,
                              const float* __restrict__ maskw, const float* __restrict__ maskb,
                              float* __restrict__ offset, float* __restrict__ mask) {
    int idx = blockIdx.x * blockDim.x + threadIdx.x;
    if (idx >= B_ * 27 * HW_) return;
    int pix = idx % HW_;
    int t   = idx / HW_;
    int oc  = t % 27;
    int b   = t / 27;
    int h = pix / W_, w = pix % W_;
    const float* wgt = (oc < 18) ? (offw + (size_t)oc * C_ * 9)
                                 : (maskw + (size_t)(oc - 18) * C_ * 9);
    float acc = (oc < 18) ? offb[oc] : maskb[oc - 18];
    const float* xb = xn + (size_t)b * C_ * HW_;
    for (int ic = 0; ic < C_; ++ic) {
        const float* xc = xb + (size_t)ic * HW_;
        const float* wc = wgt + ic * 9;
        #pragma unroll
        for (int ky = 0; ky < 3; ++ky) {
            int y = h + ky - 1;
            if ((unsigned)y >= (unsigned)H_) continue;
            #pragma unroll
            for (int kx = 0; kx < 3; ++kx) {
                int xw = w + kx - 1;
                if ((unsigned)xw >= (unsigned)W_) continue;
                acc += xc[y * W_ + xw] * wc[ky * 3 + kx];
            }
        }
    }
    if (oc < 18) {
        offset[((size_t)b * 18 + oc) * HW_ + pix] = acc;
    } else {
        mask[((size_t)b * 9 + (oc - 18)) * HW_ + pix] = 1.f / (1.f + expf(-acc));
    }
}

// ---------------- modulated deformable conv (64->64) ----------------
// one 64-thread block per output pixel
__global__ void deform_kernel(const float* __restrict__ xn,
                              const float* __restrict__ offset,
                              const float* __restrict__ mask,
                              const float* __restrict__ dw,
                              const float* __restrict__ db,
                              float* __restrict__ xdef) {
    __shared__ float sval[C_][KK_];
    __shared__ float sdy[KK_], sdx[KK_], sm[KK_];
    int p = blockIdx.x;                 // [0, B*HW)
    int b = p / HW_, pix = p % HW_;
    int h = pix / W_, w = pix % W_;
    int t = threadIdx.x;                // 0..63
    if (t < KK_) {
        sdy[t] = offset[((size_t)b * 18 + 2 * t) * HW_ + pix];
        sdx[t] = offset[((size_t)b * 18 + 2 * t + 1) * HW_ + pix];
        sm[t]  = mask[((size_t)b * 9 + t) * HW_ + pix];
    }
    __syncthreads();

    // phase A: thread = input channel, compute 9 modulated bilinear samples
    const float* xc = xn + ((size_t)b * C_ + t) * HW_;
    #pragma unroll
    for (int k = 0; k < KK_; ++k) {
        float py = sdy[k] + (float)(h - 1 + k / 3);
        float px = sdx[k] + (float)(w - 1 + k % 3);
        float y0f = floorf(py), x0f = floorf(px);
        float ly = py - y0f, lx = px - x0f;
        int y0 = (int)y0f, x0 = (int)x0f;
        float w00 = (1.f - ly) * (1.f - lx);
        float w01 = (1.f - ly) * lx;
        float w10 = ly * (1.f - lx);
        float w11 = ly * lx;
        float v = 0.f;
        if ((unsigned)y0 < (unsigned)H_ && (unsigned)x0 < (unsigned)W_)
            v += w00 * xc[y0 * W_ + x0];
        if ((unsigned)y0 < (unsigned)H_ && (unsigned)(x0 + 1) < (unsigned)W_)
            v += w01 * xc[y0 * W_ + x0 + 1];
        if ((unsigned)(y0 + 1) < (unsigned)H_ && (unsigned)x0 < (unsigned)W_)
            v += w10 * xc[(y0 + 1) * W_ + x0];
        if ((unsigned)(y0 + 1) < (unsigned)H_ && (unsigned)(x0 + 1) < (unsigned)W_)
            v += w11 * xc[(y0 + 1) * W_ + x0 + 1];
        sval[t][k] = v * sm[k];
    }
    __syncthreads();

    // phase B: thread = output channel, contract over (c,k)
    float acc = db[t];
    const float* wo = dw + (size_t)t * C_ * KK_;
    for (int c = 0; c < C_; ++c) {
        #pragma unroll
        for (int k = 0; k < KK_; ++k) acc += sval[c][k] * wo[c * KK_ + k];
    }
    xdef[((size_t)b * C_ + t) * HW_ + pix] = acc;
}

// ---------------- fusion conv + pre_mask blend ----------------
__global__ void fuse_kernel(const float* __restrict__ xdef,
                            const float* __restrict__ fw, const float* __restrict__ fb,
                            const float* __restrict__ premask,
                            const float* __restrict__ xin,
                            float* __restrict__ out) {
    int idx = blockIdx.x * blockDim.x + threadIdx.x;
    if (idx >= B_ * C_ * HW_) return;
    int pix = idx % HW_;
    int t   = idx / HW_;
    int oc  = t % C_;
    int b   = t / C_;
    int h = pix / W_, w = pix % W_;
    float acc = fb[oc];
    const float* xb  = xdef + (size_t)b * C_ * HW_;
    const float* wgt = fw + (size_t)oc * C_ * 9;
    for (int ic = 0; ic < C_; ++ic) {
        const float* xc = xb + (size_t)ic * HW_;
        const float* wc = wgt + ic * 9;
        #pragma unroll
        for (int ky = 0; ky < 3; ++ky) {
            int y = h + ky - 1;
            if ((unsigned)y >= (unsigned)H_) continue;
            #pragma unroll
            for (int kx = 0; kx < 3; ++kx) {
                int xw = w + kx - 1;
                if ((unsigned)xw >= (unsigned)W_) continue;
                acc += xc[y * W_ + xw] * wc[ky * 3 + kx];
            }
        }
    }
    float pm = premask[(size_t)b * HW_ + pix];
    out[idx] = acc * pm + xin[idx] * (1.f - pm);
}

extern "C" void kernel_launch(void* const* d_in, const int* in_sizes, int n_in,
                              void* d_out, int out_size, void* d_ws, size_t ws_size,
                              hipStream_t stream) {
    const float* x       = (const float*)d_in[0];
    const float* premask = (const float*)d_in[1];
    const float* lnw     = (const float*)d_in[2];
    const float* lnb     = (const float*)d_in[3];
    const float* offw    = (const float*)d_in[4];
    const float* offb    = (const float*)d_in[5];
    const float* maskw   = (const float*)d_in[6];
    const float* maskb   = (const float*)d_in[7];
    const float* dw      = (const float*)d_in[8];
    const float* db      = (const float*)d_in[9];
    const float* fw      = (const float*)d_in[10];
    const float* fb      = (const float*)d_in[11];
    float* out = (float*)d_out;

    float* ws     = (float*)d_ws;
    float* xn     = ws;
    float* offset = xn + (size_t)B_ * C_ * HW_;
    float* mask   = offset + (size_t)B_ * 18 * HW_;
    float* xdef   = mask + (size_t)B_ * 9 * HW_;

    ln_kernel<<<(B_ * HW_ + 255) / 256, 256, 0, stream>>>(x, lnw, lnb, xn);
    conv27_kernel<<<(B_ * 27 * HW_ + 255) / 256, 256, 0, stream>>>(
        xn, offw, offb, maskw, maskb, offset, mask);
    deform_kernel<<<B_ * HW_, 64, 0, stream>>>(xn, offset, mask, dw, db, xdef);
    fuse_kernel<<<(B_ * C_ * HW_ + 255) / 256, 256, 0, stream>>>(
        xdef, fw, fb, premask, x, out);
}

// Round 2
// 944.920 us; speedup vs baseline: 3.0392x; 3.0392x over previous
//
#include <hip/hip_runtime.h>
#include <math.h>

#define B_ 2
#define C_ 64
#define H_ 192
#define W_ 192
#define HW_ (H_*W_)
#define BHW_ (B_*HW_)
#define KK_ 9

// ---------------- LayerNorm over channel axis ----------------
__global__ void ln_kernel(const float* __restrict__ x,
                          const float* __restrict__ lnw,
                          const float* __restrict__ lnb,
                          float* __restrict__ xn) {
    int p = blockIdx.x * blockDim.x + threadIdx.x;   // pixel in [0, B*HW)
    if (p >= BHW_) return;
    int b = p / HW_, pix = p % HW_;
    const float* xb = x + (size_t)b * C_ * HW_ + pix;
    float v[C_];
    float s = 0.f, s2 = 0.f;
    #pragma unroll
    for (int c = 0; c < C_; ++c) {
        v[c] = xb[(size_t)c * HW_];
        s += v[c]; s2 += v[c] * v[c];
    }
    float mu  = s * (1.0f / C_);
    float var = s2 * (1.0f / C_) - mu * mu;
    float inv = rsqrtf(var + 1e-5f);
    float* yb = xn + (size_t)b * C_ * HW_ + pix;
    #pragma unroll
    for (int c = 0; c < C_; ++c) {
        yb[(size_t)c * HW_] = (v[c] - mu) * inv * lnw[c] + lnb[c];
    }
}

// ---------------- offset(18ch) + mask(9ch, sigmoid) 3x3 conv ----------------
// thread = pixel; 3 oc-groups of 9; weights via wave-uniform (scalar) loads
__global__ void conv27_kernel(const float* __restrict__ xn,
                              const float* __restrict__ offw, const float* __restrict__ offb,
                              const float* __restrict__ maskw, const float* __restrict__ maskb,
                              float* __restrict__ offset, float* __restrict__ mask) {
    int tid = blockIdx.x * blockDim.x + threadIdx.x;
    if (tid >= 3 * BHW_) return;
    int gg = tid / BHW_;                 // wave-uniform (BHW_ % 64 == 0)
    int p  = tid - gg * BHW_;
    int g  = __builtin_amdgcn_readfirstlane(gg);
    int b = p / HW_, pix = p % HW_;
    int h = pix / W_, w = pix % W_;

    const float* wsel = (g < 2) ? (offw + (size_t)g * 9 * C_ * 9) : maskw;
    const float* bsel = (g < 2) ? (offb + g * 9) : maskb;

    // per-pixel tap addresses + validity
    int   aoff[KK_];
    bool  vok[KK_];
    #pragma unroll
    for (int k = 0; k < KK_; ++k) {
        int yy = h + k / 3 - 1, xx = w + k % 3 - 1;
        bool ok = ((unsigned)yy < (unsigned)H_) && ((unsigned)xx < (unsigned)W_);
        vok[k] = ok;
        aoff[k] = (ok ? yy : 0) * W_ + (ok ? xx : 0);
    }

    float acc[9];
    #pragma unroll
    for (int i = 0; i < 9; ++i) acc[i] = bsel[i];

    const float* xb = xn + (size_t)b * C_ * HW_;
    for (int ic = 0; ic < C_; ++ic) {
        const float* xc = xb + (size_t)ic * HW_;
        float in[KK_];
        #pragma unroll
        for (int k = 0; k < KK_; ++k) in[k] = vok[k] ? xc[aoff[k]] : 0.f;
        const float* wic = wsel + ic * 9;
        #pragma unroll
        for (int i = 0; i < 9; ++i) {
            #pragma unroll
            for (int k = 0; k < KK_; ++k)
                acc[i] += in[k] * wic[(size_t)i * C_ * 9 + k];
        }
    }

    if (g < 2) {
        #pragma unroll
        for (int i = 0; i < 9; ++i)
            offset[((size_t)b * 18 + g * 9 + i) * HW_ + pix] = acc[i];
    } else {
        #pragma unroll
        for (int i = 0; i < 9; ++i)
            mask[((size_t)b * 9 + i) * HW_ + pix] = 1.f / (1.f + expf(-acc[i]));
    }
}

// ---------------- modulated deformable conv (64->64) ----------------
// thread = (pixel, oc-half of 32); gathers in VGPR, weights via scalar loads
__global__ void deform_kernel(const float* __restrict__ xn,
                              const float* __restrict__ offset,
                              const float* __restrict__ mask,
                              const float* __restrict__ dw,
                              const float* __restrict__ db,
                              float* __restrict__ xdef) {
    int tid = blockIdx.x * blockDim.x + threadIdx.x;
    if (tid >= 2 * BHW_) return;
    int ohh = tid / BHW_;               // wave-uniform
    int p   = tid - ohh * BHW_;
    int ocb = __builtin_amdgcn_readfirstlane(ohh) * 32;
    int b = p / HW_, pix = p % HW_;
    int h = pix / W_, w = pix % W_;

    // per-pixel: 9 taps, 4 corners each: clamped addr + validity-zeroed,
    // mask-premultiplied bilinear weights
    int   a00[KK_], a01[KK_], a10[KK_], a11[KK_];
    float q00[KK_], q01[KK_], q10[KK_], q11[KK_];
    #pragma unroll
    for (int k = 0; k < KK_; ++k) {
        float dy = offset[((size_t)b * 18 + 2 * k) * HW_ + pix];
        float dx = offset[((size_t)b * 18 + 2 * k + 1) * HW_ + pix];
        float m  = mask[((size_t)b * 9 + k) * HW_ + pix];
        float py = dy + (float)(h - 1 + k / 3);
        float px = dx + (float)(w - 1 + k % 3);
        float fy = floorf(py), fx = floorf(px);
        float ly = py - fy, lx = px - fx;
        int y0 = (int)fy, x0 = (int)fx;
        int y1 = y0 + 1, x1 = x0 + 1;
        bool oky0 = (unsigned)y0 < (unsigned)H_;
        bool oky1 = (unsigned)y1 < (unsigned)H_;
        bool okx0 = (unsigned)x0 < (unsigned)W_;
        bool okx1 = (unsigned)x1 < (unsigned)W_;
        int cy0 = min(max(y0, 0), H_ - 1), cy1 = min(max(y1, 0), H_ - 1);
        int cx0 = min(max(x0, 0), W_ - 1), cx1 = min(max(x1, 0), W_ - 1);
        a00[k] = cy0 * W_ + cx0; a01[k] = cy0 * W_ + cx1;
        a10[k] = cy1 * W_ + cx0; a11[k] = cy1 * W_ + cx1;
        float w00 = (1.f - ly) * (1.f - lx) * m, w01 = (1.f - ly) * lx * m;
        float w10 = ly * (1.f - lx) * m,         w11 = ly * lx * m;
        q00[k] = (oky0 && okx0) ? w00 : 0.f;
        q01[k] = (oky0 && okx1) ? w01 : 0.f;
        q10[k] = (oky1 && okx0) ? w10 : 0.f;
        q11[k] = (oky1 && okx1) ? w11 : 0.f;
    }

    float acc[32];
    #pragma unroll
    for (int i = 0; i < 32; ++i) acc[i] = db[ocb + i];

    const float* xb = xn + (size_t)b * C_ * HW_;
    const float* wb = dw + (size_t)ocb * C_ * 9;
    for (int ic = 0; ic < C_; ++ic) {
        const float* xc = xb + (size_t)ic * HW_;
        float sv[KK_];
        #pragma unroll
        for (int k = 0; k < KK_; ++k) {
            sv[k] = q00[k] * xc[a00[k]] + q01[k] * xc[a01[k]]
                  + q10[k] * xc[a10[k]] + q11[k] * xc[a11[k]];
        }
        const float* wic = wb + (size_t)ic * 9;
        #pragma unroll
        for (int i = 0; i < 32; ++i) {
            #pragma unroll
            for (int k = 0; k < KK_; ++k)
                acc[i] += sv[k] * wic[(size_t)i * C_ * 9 + k];
        }
    }

    #pragma unroll
    for (int i = 0; i < 32; ++i)
        xdef[((size_t)b * C_ + ocb + i) * HW_ + pix] = acc[i];
}

// ---------------- fusion conv + pre_mask blend ----------------
// thread = (pixel, oc-half of 32)
__global__ void fuse_kernel(const float* __restrict__ xdef,
                            const float* __restrict__ fw, const float* __restrict__ fb,
                            const float* __restrict__ premask,
                            const float* __restrict__ xin,
                            float* __restrict__ out) {
    int tid = blockIdx.x * blockDim.x + threadIdx.x;
    if (tid >= 2 * BHW_) return;
    int ohh = tid / BHW_;               // wave-uniform
    int p   = tid - ohh * BHW_;
    int ocb = __builtin_amdgcn_readfirstlane(ohh) * 32;
    int b = p / HW_, pix = p % HW_;
    int h = pix / W_, w = pix % W_;

    int   aoff[KK_];
    bool  vok[KK_];
    #pragma unroll
    for (int k = 0; k < KK_; ++k) {
        int yy = h + k / 3 - 1, xx = w + k % 3 - 1;
        bool ok = ((unsigned)yy < (unsigned)H_) && ((unsigned)xx < (unsigned)W_);
        vok[k] = ok;
        aoff[k] = (ok ? yy : 0) * W_ + (ok ? xx : 0);
    }

    float acc[32];
    #pragma unroll
    for (int i = 0; i < 32; ++i) acc[i] = fb[ocb + i];

    const float* xb = xdef + (size_t)b * C_ * HW_;
    const float* wb = fw + (size_t)ocb * C_ * 9;
    for (int ic = 0; ic < C_; ++ic) {
        const float* xc = xb + (size_t)ic * HW_;
        float in[KK_];
        #pragma unroll
        for (int k = 0; k < KK_; ++k) in[k] = vok[k] ? xc[aoff[k]] : 0.f;
        const float* wic = wb + (size_t)ic * 9;
        #pragma unroll
        for (int i = 0; i < 32; ++i) {
            #pragma unroll
            for (int k = 0; k < KK_; ++k)
                acc[i] += in[k] * wic[(size_t)i * C_ * 9 + k];
        }
    }

    float pm = premask[(size_t)b * HW_ + pix];
    #pragma unroll
    for (int i = 0; i < 32; ++i) {
        size_t oidx = ((size_t)b * C_ + ocb + i) * HW_ + pix;
        out[oidx] = acc[i] * pm + xin[oidx] * (1.f - pm);
    }
}

extern "C" void kernel_launch(void* const* d_in, const int* in_sizes, int n_in,
                              void* d_out, int out_size, void* d_ws, size_t ws_size,
                              hipStream_t stream) {
    const float* x       = (const float*)d_in[0];
    const float* premask = (const float*)d_in[1];
    const float* lnw     = (const float*)d_in[2];
    const float* lnb     = (const float*)d_in[3];
    const float* offw    = (const float*)d_in[4];
    const float* offb    = (const float*)d_in[5];
    const float* maskw   = (const float*)d_in[6];
    const float* maskb   = (const float*)d_in[7];
    const float* dw      = (const float*)d_in[8];
    const float* db      = (const float*)d_in[9];
    const float* fw      = (const float*)d_in[10];
    const float* fb      = (const float*)d_in[11];
    float* out = (float*)d_out;

    float* ws     = (float*)d_ws;
    float* xn     = ws;
    float* offset = xn + (size_t)B_ * C_ * HW_;
    float* mask   = offset + (size_t)B_ * 18 * HW_;
    float* xdef   = mask + (size_t)B_ * 9 * HW_;

    ln_kernel<<<(BHW_ + 255) / 256, 256, 0, stream>>>(x, lnw, lnb, xn);
    conv27_kernel<<<(3 * BHW_ + 255) / 256, 256, 0, stream>>>(
        xn, offw, offb, maskw, maskb, offset, mask);
    deform_kernel<<<(2 * BHW_ + 255) / 256, 256, 0, stream>>>(
        xn, offset, mask, dw, db, xdef);
    fuse_kernel<<<(2 * BHW_ + 255) / 256, 256, 0, stream>>>(
        xdef, fw, fb, premask, x, out);
}

// Round 3
// 598.589 us; speedup vs baseline: 4.7976x; 1.5786x over previous
//
#include <hip/hip_runtime.h>
#include <hip/hip_bf16.h>
#include <math.h>

#define B_ 2
#define C_ 64
#define H_ 192
#define W_ 192
#define HW_ (H_*W_)
#define BHW_ (B_*HW_)
#define KK_ 9
#define CK_ (C_*KK_)   // 576

// ---------------- LayerNorm over channel axis ----------------
__global__ void ln_kernel(const float* __restrict__ x,
                          const float* __restrict__ lnw,
                          const float* __restrict__ lnb,
                          float* __restrict__ xn) {
    int p = blockIdx.x * blockDim.x + threadIdx.x;
    if (p >= BHW_) return;
    int b = p / HW_, pix = p % HW_;
    const float* xb = x + (size_t)b * C_ * HW_ + pix;
    float v[C_];
    float s = 0.f, s2 = 0.f;
    #pragma unroll
    for (int c = 0; c < C_; ++c) {
        v[c] = xb[(size_t)c * HW_];
        s += v[c]; s2 += v[c] * v[c];
    }
    float mu  = s * (1.0f / C_);
    float var = s2 * (1.0f / C_) - mu * mu;
    float inv = rsqrtf(var + 1e-5f);
    float* yb = xn + (size_t)b * C_ * HW_ + pix;
    #pragma unroll
    for (int c = 0; c < C_; ++c) {
        yb[(size_t)c * HW_] = (v[c] - mu) * inv * lnw[c] + lnb[c];
    }
}

// ---------------- offset(18ch) + mask(9ch, sigmoid) 3x3 conv ----------------
__global__ void conv27_kernel(const float* __restrict__ xn,
                              const float* __restrict__ offw, const float* __restrict__ offb,
                              const float* __restrict__ maskw, const float* __restrict__ maskb,
                              float* __restrict__ offset, float* __restrict__ mask) {
    int tid = blockIdx.x * blockDim.x + threadIdx.x;
    if (tid >= 3 * BHW_) return;
    int gg = tid / BHW_;
    int p  = tid - gg * BHW_;
    int g  = __builtin_amdgcn_readfirstlane(gg);
    int b = p / HW_, pix = p % HW_;
    int h = pix / W_, w = pix % W_;

    const float* wsel = (g < 2) ? (offw + (size_t)g * 9 * C_ * 9) : maskw;
    const float* bsel = (g < 2) ? (offb + g * 9) : maskb;

    int   aoff[KK_];
    bool  vok[KK_];
    #pragma unroll
    for (int k = 0; k < KK_; ++k) {
        int yy = h + k / 3 - 1, xx = w + k % 3 - 1;
        bool ok = ((unsigned)yy < (unsigned)H_) && ((unsigned)xx < (unsigned)W_);
        vok[k] = ok;
        aoff[k] = (ok ? yy : 0) * W_ + (ok ? xx : 0);
    }

    float acc[9];
    #pragma unroll
    for (int i = 0; i < 9; ++i) acc[i] = bsel[i];

    const float* xb = xn + (size_t)b * C_ * HW_;
    for (int ic = 0; ic < C_; ++ic) {
        const float* xc = xb + (size_t)ic * HW_;
        float in[KK_];
        #pragma unroll
        for (int k = 0; k < KK_; ++k) in[k] = vok[k] ? xc[aoff[k]] : 0.f;
        const float* wic = wsel + ic * 9;
        #pragma unroll
        for (int i = 0; i < 9; ++i) {
            #pragma unroll
            for (int k = 0; k < KK_; ++k)
                acc[i] += in[k] * wic[(size_t)i * C_ * 9 + k];
        }
    }

    if (g < 2) {
        #pragma unroll
        for (int i = 0; i < 9; ++i)
            offset[((size_t)b * 18 + g * 9 + i) * HW_ + pix] = acc[i];
    } else {
        #pragma unroll
        for (int i = 0; i < 9; ++i)
            mask[((size_t)b * 9 + i) * HW_ + pix] = 1.f / (1.f + expf(-acc[i]));
    }
}

// ---------------- D1: modulated bilinear gather -> im2col (bf16) ----------------
// thread = (tap k, pixel); writes val[(c*9+k)][p] for all c
__global__ void gather_kernel(const float* __restrict__ xn,
                              const float* __restrict__ offset,
                              const float* __restrict__ mask,
                              __hip_bfloat16* __restrict__ val) {
    int tid = blockIdx.x * blockDim.x + threadIdx.x;
    if (tid >= KK_ * BHW_) return;
    int kk = tid / BHW_;                 // wave-uniform (BHW_ % 64 == 0)
    int p  = tid - kk * BHW_;
    kk = __builtin_amdgcn_readfirstlane(kk);
    int b = p / HW_, pix = p % HW_;
    int h = pix / W_, w = pix % W_;

    float dy = offset[((size_t)b * 18 + 2 * kk) * HW_ + pix];
    float dx = offset[((size_t)b * 18 + 2 * kk + 1) * HW_ + pix];
    float m  = mask[((size_t)b * 9 + kk) * HW_ + pix];

    float py = dy + (float)(h - 1 + kk / 3);
    float px = dx + (float)(w - 1 + kk % 3);
    float fy = floorf(py), fx = floorf(px);
    float ly = py - fy, lx = px - fx;
    int y0 = (int)fy, x0 = (int)fx;
    int y1 = y0 + 1, x1 = x0 + 1;
    bool oky0 = (unsigned)y0 < (unsigned)H_;
    bool oky1 = (unsigned)y1 < (unsigned)H_;
    bool okx0 = (unsigned)x0 < (unsigned)W_;
    bool okx1 = (unsigned)x1 < (unsigned)W_;
    int cy0 = min(max(y0, 0), H_ - 1), cy1 = min(max(y1, 0), H_ - 1);
    int cx0 = min(max(x0, 0), W_ - 1), cx1 = min(max(x1, 0), W_ - 1);
    int a00 = cy0 * W_ + cx0, a01 = cy0 * W_ + cx1;
    int a10 = cy1 * W_ + cx0, a11 = cy1 * W_ + cx1;
    float q00 = (oky0 && okx0) ? (1.f - ly) * (1.f - lx) * m : 0.f;
    float q01 = (oky0 && okx1) ? (1.f - ly) * lx * m : 0.f;
    float q10 = (oky1 && okx0) ? ly * (1.f - lx) * m : 0.f;
    float q11 = (oky1 && okx1) ? ly * lx * m : 0.f;

    const float* xb = xn + (size_t)b * C_ * HW_;
    __hip_bfloat16* vb = val + p;
    #pragma unroll 4
    for (int c = 0; c < C_; ++c) {
        const float* xc = xb + (size_t)c * HW_;
        float v = q00 * xc[a00] + q01 * xc[a01] + q10 * xc[a10] + q11 * xc[a11];
        vb[(size_t)(c * KK_ + kk) * BHW_] = __float2bfloat16(v);
    }
}

// ---------------- D2: contraction out[o,p] = sum_ck w[o,ck] val[ck,p] ----------
// thread = (oc-half, pixel); weights via wave-uniform scalar loads
__global__ void contract_kernel(const __hip_bfloat16* __restrict__ val,
                                const float* __restrict__ dw,
                                const float* __restrict__ db,
                                float* __restrict__ xdef) {
    int tid = blockIdx.x * blockDim.x + threadIdx.x;
    if (tid >= 2 * BHW_) return;
    int g = tid / BHW_;
    int p = tid - g * BHW_;
    int ocb = __builtin_amdgcn_readfirstlane(g) * 32;

    float acc[32];
    #pragma unroll
    for (int i = 0; i < 32; ++i) acc[i] = db[ocb + i];

    const float* wb = dw + (size_t)ocb * CK_;
    const __hip_bfloat16* vp = val + p;
    for (int ck = 0; ck < CK_; ck += 4) {
        float v0 = __bfloat162float(vp[(size_t)(ck + 0) * BHW_]);
        float v1 = __bfloat162float(vp[(size_t)(ck + 1) * BHW_]);
        float v2 = __bfloat162float(vp[(size_t)(ck + 2) * BHW_]);
        float v3 = __bfloat162float(vp[(size_t)(ck + 3) * BHW_]);
        #pragma unroll
        for (int i = 0; i < 32; ++i) {
            const float* wr = wb + (size_t)i * CK_ + ck;
            acc[i] += v0 * wr[0] + v1 * wr[1] + v2 * wr[2] + v3 * wr[3];
        }
    }

    int b = p / HW_, pix = p % HW_;
    #pragma unroll
    for (int i = 0; i < 32; ++i)
        xdef[((size_t)b * C_ + ocb + i) * HW_ + pix] = acc[i];
}

// ---------------- fusion conv + pre_mask blend ----------------
__global__ void fuse_kernel(const float* __restrict__ xdef,
                            const float* __restrict__ fw, const float* __restrict__ fb,
                            const float* __restrict__ premask,
                            const float* __restrict__ xin,
                            float* __restrict__ out) {
    int tid = blockIdx.x * blockDim.x + threadIdx.x;
    if (tid >= 2 * BHW_) return;
    int ohh = tid / BHW_;
    int p   = tid - ohh * BHW_;
    int ocb = __builtin_amdgcn_readfirstlane(ohh) * 32;
    int b = p / HW_, pix = p % HW_;
    int h = pix / W_, w = pix % W_;

    int   aoff[KK_];
    bool  vok[KK_];
    #pragma unroll
    for (int k = 0; k < KK_; ++k) {
        int yy = h + k / 3 - 1, xx = w + k % 3 - 1;
        bool ok = ((unsigned)yy < (unsigned)H_) && ((unsigned)xx < (unsigned)W_);
        vok[k] = ok;
        aoff[k] = (ok ? yy : 0) * W_ + (ok ? xx : 0);
    }

    float acc[32];
    #pragma unroll
    for (int i = 0; i < 32; ++i) acc[i] = fb[ocb + i];

    const float* xb = xdef + (size_t)b * C_ * HW_;
    const float* wb = fw + (size_t)ocb * C_ * 9;
    for (int ic = 0; ic < C_; ++ic) {
        const float* xc = xb + (size_t)ic * HW_;
        float in[KK_];
        #pragma unroll
        for (int k = 0; k < KK_; ++k) in[k] = vok[k] ? xc[aoff[k]] : 0.f;
        const float* wic = wb + (size_t)ic * 9;
        #pragma unroll
        for (int i = 0; i < 32; ++i) {
            #pragma unroll
            for (int k = 0; k < KK_; ++k)
                acc[i] += in[k] * wic[(size_t)i * C_ * 9 + k];
        }
    }

    float pm = premask[(size_t)b * HW_ + pix];
    #pragma unroll
    for (int i = 0; i < 32; ++i) {
        size_t oidx = ((size_t)b * C_ + ocb + i) * HW_ + pix;
        out[oidx] = acc[i] * pm + xin[oidx] * (1.f - pm);
    }
}

extern "C" void kernel_launch(void* const* d_in, const int* in_sizes, int n_in,
                              void* d_out, int out_size, void* d_ws, size_t ws_size,
                              hipStream_t stream) {
    const float* x       = (const float*)d_in[0];
    const float* premask = (const float*)d_in[1];
    const float* lnw     = (const float*)d_in[2];
    const float* lnb     = (const float*)d_in[3];
    const float* offw    = (const float*)d_in[4];
    const float* offb    = (const float*)d_in[5];
    const float* maskw   = (const float*)d_in[6];
    const float* maskb   = (const float*)d_in[7];
    const float* dw      = (const float*)d_in[8];
    const float* db      = (const float*)d_in[9];
    const float* fw      = (const float*)d_in[10];
    const float* fb      = (const float*)d_in[11];
    float* out = (float*)d_out;

    float* ws     = (float*)d_ws;
    float* xn     = ws;                                   // 18.9 MB
    float* offset = xn + (size_t)B_ * C_ * HW_;           // 5.3 MB
    float* mask   = offset + (size_t)B_ * 18 * HW_;       // 2.7 MB
    float* xdef   = mask + (size_t)B_ * 9 * HW_;          // 18.9 MB
    __hip_bfloat16* val = (__hip_bfloat16*)(xdef + (size_t)B_ * C_ * HW_);  // 85 MB

    ln_kernel<<<(BHW_ + 255) / 256, 256, 0, stream>>>(x, lnw, lnb, xn);
    conv27_kernel<<<(3 * BHW_ + 255) / 256, 256, 0, stream>>>(
        xn, offw, offb, maskw, maskb, offset, mask);
    gather_kernel<<<(KK_ * BHW_ + 255) / 256, 256, 0, stream>>>(
        xn, offset, mask, val);
    contract_kernel<<<(2 * BHW_ + 255) / 256, 256, 0, stream>>>(
        val, dw, db, xdef);
    fuse_kernel<<<(2 * BHW_ + 255) / 256, 256, 0, stream>>>(
        xdef, fw, fb, premask, x, out);
}

// Round 4
// 406.770 us; speedup vs baseline: 7.0600x; 1.4716x over previous
//
#include <hip/hip_runtime.h>
#include <hip/hip_bf16.h>
#include <math.h>

#define B_ 2
#define C_ 64
#define H_ 192
#define W_ 192
#define HW_ (H_*W_)
#define BHW_ (B_*HW_)
#define KK_ 9
#define CK_ (C_*KK_)   // 576
#define KSTEPS_ (CK_/32)  // 18

typedef __bf16 bf16x8 __attribute__((ext_vector_type(8)));
typedef float  f32x4  __attribute__((ext_vector_type(4)));

// ---------------- LayerNorm over channel axis ----------------
__global__ void ln_kernel(const float* __restrict__ x,
                          const float* __restrict__ lnw,
                          const float* __restrict__ lnb,
                          float* __restrict__ xn) {
    int p = blockIdx.x * blockDim.x + threadIdx.x;
    if (p >= BHW_) return;
    int b = p / HW_, pix = p % HW_;
    const float* xb = x + (size_t)b * C_ * HW_ + pix;
    float v[C_];
    float s = 0.f, s2 = 0.f;
    #pragma unroll
    for (int c = 0; c < C_; ++c) {
        v[c] = xb[(size_t)c * HW_];
        s += v[c]; s2 += v[c] * v[c];
    }
    float mu  = s * (1.0f / C_);
    float var = s2 * (1.0f / C_) - mu * mu;
    float inv = rsqrtf(var + 1e-5f);
    float* yb = xn + (size_t)b * C_ * HW_ + pix;
    #pragma unroll
    for (int c = 0; c < C_; ++c) {
        yb[(size_t)c * HW_] = (v[c] - mu) * inv * lnw[c] + lnb[c];
    }
}

// ---------------- offset(18ch) + mask(9ch, sigmoid) 3x3 conv ----------------
__global__ void conv27_kernel(const float* __restrict__ xn,
                              const float* __restrict__ offw, const float* __restrict__ offb,
                              const float* __restrict__ maskw, const float* __restrict__ maskb,
                              float* __restrict__ offset, float* __restrict__ mask) {
    int tid = blockIdx.x * blockDim.x + threadIdx.x;
    if (tid >= 3 * BHW_) return;
    int gg = tid / BHW_;
    int p  = tid - gg * BHW_;
    int g  = __builtin_amdgcn_readfirstlane(gg);
    int b = p / HW_, pix = p % HW_;
    int h = pix / W_, w = pix % W_;

    const float* wsel = (g < 2) ? (offw + (size_t)g * 9 * C_ * 9) : maskw;
    const float* bsel = (g < 2) ? (offb + g * 9) : maskb;

    int   aoff[KK_];
    bool  vok[KK_];
    #pragma unroll
    for (int k = 0; k < KK_; ++k) {
        int yy = h + k / 3 - 1, xx = w + k % 3 - 1;
        bool ok = ((unsigned)yy < (unsigned)H_) && ((unsigned)xx < (unsigned)W_);
        vok[k] = ok;
        aoff[k] = (ok ? yy : 0) * W_ + (ok ? xx : 0);
    }

    float acc[9];
    #pragma unroll
    for (int i = 0; i < 9; ++i) acc[i] = bsel[i];

    const float* xb = xn + (size_t)b * C_ * HW_;
    for (int ic = 0; ic < C_; ++ic) {
        const float* xc = xb + (size_t)ic * HW_;
        float in[KK_];
        #pragma unroll
        for (int k = 0; k < KK_; ++k) in[k] = vok[k] ? xc[aoff[k]] : 0.f;
        const float* wic = wsel + ic * 9;
        #pragma unroll
        for (int i = 0; i < 9; ++i) {
            #pragma unroll
            for (int k = 0; k < KK_; ++k)
                acc[i] += in[k] * wic[(size_t)i * C_ * 9 + k];
        }
    }

    if (g < 2) {
        #pragma unroll
        for (int i = 0; i < 9; ++i)
            offset[((size_t)b * 18 + g * 9 + i) * HW_ + pix] = acc[i];
    } else {
        #pragma unroll
        for (int i = 0; i < 9; ++i)
            mask[((size_t)b * 9 + i) * HW_ + pix] = 1.f / (1.f + expf(-acc[i]));
    }
}

// ---------------- D1: modulated bilinear gather -> im2col (bf16) ----------------
__global__ void gather_kernel(const float* __restrict__ xn,
                              const float* __restrict__ offset,
                              const float* __restrict__ mask,
                              __hip_bfloat16* __restrict__ val) {
    int tid = blockIdx.x * blockDim.x + threadIdx.x;
    if (tid >= KK_ * BHW_) return;
    int kk = tid / BHW_;
    int p  = tid - kk * BHW_;
    kk = __builtin_amdgcn_readfirstlane(kk);
    int b = p / HW_, pix = p % HW_;
    int h = pix / W_, w = pix % W_;

    float dy = offset[((size_t)b * 18 + 2 * kk) * HW_ + pix];
    float dx = offset[((size_t)b * 18 + 2 * kk + 1) * HW_ + pix];
    float m  = mask[((size_t)b * 9 + kk) * HW_ + pix];

    float py = dy + (float)(h - 1 + kk / 3);
    float px = dx + (float)(w - 1 + kk % 3);
    float fy = floorf(py), fx = floorf(px);
    float ly = py - fy, lx = px - fx;
    int y0 = (int)fy, x0 = (int)fx;
    int y1 = y0 + 1, x1 = x0 + 1;
    bool oky0 = (unsigned)y0 < (unsigned)H_;
    bool oky1 = (unsigned)y1 < (unsigned)H_;
    bool okx0 = (unsigned)x0 < (unsigned)W_;
    bool okx1 = (unsigned)x1 < (unsigned)W_;
    int cy0 = min(max(y0, 0), H_ - 1), cy1 = min(max(y1, 0), H_ - 1);
    int cx0 = min(max(x0, 0), W_ - 1), cx1 = min(max(x1, 0), W_ - 1);
    int a00 = cy0 * W_ + cx0, a01 = cy0 * W_ + cx1;
    int a10 = cy1 * W_ + cx0, a11 = cy1 * W_ + cx1;
    float q00 = (oky0 && okx0) ? (1.f - ly) * (1.f - lx) * m : 0.f;
    float q01 = (oky0 && okx1) ? (1.f - ly) * lx * m : 0.f;
    float q10 = (oky1 && okx0) ? ly * (1.f - lx) * m : 0.f;
    float q11 = (oky1 && okx1) ? ly * lx * m : 0.f;

    const float* xb = xn + (size_t)b * C_ * HW_;
    __hip_bfloat16* vb = val + p;
    #pragma unroll 4
    for (int c = 0; c < C_; ++c) {
        const float* xc = xb + (size_t)c * HW_;
        float v = q00 * xc[a00] + q01 * xc[a01] + q10 * xc[a10] + q11 * xc[a11];
        vb[(size_t)(c * KK_ + kk) * BHW_] = __float2bfloat16(v);
    }
}

// ---------------- weight prepack: f32 OIHW -> bf16 MFMA A-fragments ----------
// wpack[((t*18 + s)*64 + lane)*8 + j] = bf16(dw[(t*16 + (lane&15))*576 + s*32 + (lane>>4)*8 + j])
__global__ void prepack_kernel(const float* __restrict__ dw,
                               unsigned short* __restrict__ wpack) {
    const int total = 4 * KSTEPS_ * 64 * 8;   // 36864
    for (int idx = threadIdx.x; idx < total; idx += blockDim.x) {
        int j = idx & 7;
        int l = (idx >> 3) & 63;
        int rest = idx >> 9;
        int s = rest % KSTEPS_;
        int t = rest / KSTEPS_;
        int oc = t * 16 + (l & 15);
        int k  = s * 32 + (l >> 4) * 8 + j;
        __hip_bfloat16 hb = __float2bfloat16(dw[(size_t)oc * CK_ + k]);
        wpack[idx] = *reinterpret_cast<unsigned short*>(&hb);
    }
}

// ---------------- D2: MFMA contraction xdef[oc,p] = W[oc,ck] . val[ck,p] -----
// block = 4 waves; wave = one 16-pixel tile x all 64 oc
__global__ void __launch_bounds__(256) contract_mfma(
        const unsigned short* __restrict__ val,
        const unsigned short* __restrict__ wpack,
        const float* __restrict__ db,
        float* __restrict__ xdef) {
    int wave = threadIdx.x >> 6;
    int lane = threadIdx.x & 63;
    int ptile = blockIdx.x * 4 + wave;       // 0..4607
    int p = ptile * 16 + (lane & 15);
    int kchunk = lane >> 4;                  // 0..3

    f32x4 acc[4];
    #pragma unroll
    for (int t = 0; t < 4; ++t) acc[t] = f32x4{0.f, 0.f, 0.f, 0.f};

    for (int s = 0; s < KSTEPS_; ++s) {
        // B-fragment: lane holds val[s*32 + kchunk*8 + j][p], j=0..7
        union { unsigned short u[8]; bf16x8 v; } bu;
        const unsigned short* vs = val + ((size_t)s * 32 + kchunk * 8) * BHW_ + p;
        #pragma unroll
        for (int j = 0; j < 8; ++j) bu.u[j] = vs[(size_t)j * BHW_];
        #pragma unroll
        for (int t = 0; t < 4; ++t) {
            bf16x8 afrag = *reinterpret_cast<const bf16x8*>(
                wpack + ((size_t)(t * KSTEPS_ + s) * 64 + lane) * 8);
            acc[t] = __builtin_amdgcn_mfma_f32_16x16x32_bf16(afrag, bu.v, acc[t], 0, 0, 0);
        }
    }

    int b = p / HW_, pix = p % HW_;
    #pragma unroll
    for (int t = 0; t < 4; ++t) {
        #pragma unroll
        for (int r = 0; r < 4; ++r) {
            int oc = t * 16 + kchunk * 4 + r;   // row = (lane>>4)*4 + r
            xdef[((size_t)b * C_ + oc) * HW_ + pix] = acc[t][r] + db[oc];
        }
    }
}

// ---------------- fusion conv + pre_mask blend ----------------
__global__ void fuse_kernel(const float* __restrict__ xdef,
                            const float* __restrict__ fw, const float* __restrict__ fb,
                            const float* __restrict__ premask,
                            const float* __restrict__ xin,
                            float* __restrict__ out) {
    int tid = blockIdx.x * blockDim.x + threadIdx.x;
    if (tid >= 2 * BHW_) return;
    int ohh = tid / BHW_;
    int p   = tid - ohh * BHW_;
    int ocb = __builtin_amdgcn_readfirstlane(ohh) * 32;
    int b = p / HW_, pix = p % HW_;
    int h = pix / W_, w = pix % W_;

    int   aoff[KK_];
    bool  vok[KK_];
    #pragma unroll
    for (int k = 0; k < KK_; ++k) {
        int yy = h + k / 3 - 1, xx = w + k % 3 - 1;
        bool ok = ((unsigned)yy < (unsigned)H_) && ((unsigned)xx < (unsigned)W_);
        vok[k] = ok;
        aoff[k] = (ok ? yy : 0) * W_ + (ok ? xx : 0);
    }

    float acc[32];
    #pragma unroll
    for (int i = 0; i < 32; ++i) acc[i] = fb[ocb + i];

    const float* xb = xdef + (size_t)b * C_ * HW_;
    const float* wb = fw + (size_t)ocb * C_ * 9;
    for (int ic = 0; ic < C_; ++ic) {
        const float* xc = xb + (size_t)ic * HW_;
        float in[KK_];
        #pragma unroll
        for (int k = 0; k < KK_; ++k) in[k] = vok[k] ? xc[aoff[k]] : 0.f;
        const float* wic = wb + (size_t)ic * 9;
        #pragma unroll
        for (int i = 0; i < 32; ++i) {
            #pragma unroll
            for (int k = 0; k < KK_; ++k)
                acc[i] += in[k] * wic[(size_t)i * C_ * 9 + k];
        }
    }

    float pm = premask[(size_t)b * HW_ + pix];
    #pragma unroll
    for (int i = 0; i < 32; ++i) {
        size_t oidx = ((size_t)b * C_ + ocb + i) * HW_ + pix;
        out[oidx] = acc[i] * pm + xin[oidx] * (1.f - pm);
    }
}

extern "C" void kernel_launch(void* const* d_in, const int* in_sizes, int n_in,
                              void* d_out, int out_size, void* d_ws, size_t ws_size,
                              hipStream_t stream) {
    const float* x       = (const float*)d_in[0];
    const float* premask = (const float*)d_in[1];
    const float* lnw     = (const float*)d_in[2];
    const float* lnb     = (const float*)d_in[3];
    const float* offw    = (const float*)d_in[4];
    const float* offb    = (const float*)d_in[5];
    const float* maskw   = (const float*)d_in[6];
    const float* maskb   = (const float*)d_in[7];
    const float* dw      = (const float*)d_in[8];
    const float* db      = (const float*)d_in[9];
    const float* fw      = (const float*)d_in[10];
    const float* fb      = (const float*)d_in[11];
    float* out = (float*)d_out;

    float* ws     = (float*)d_ws;
    float* xn     = ws;                                   // 18.9 MB
    float* offset = xn + (size_t)B_ * C_ * HW_;           // 5.3 MB
    float* mask   = offset + (size_t)B_ * 18 * HW_;       // 2.7 MB
    float* xdef   = mask + (size_t)B_ * 9 * HW_;          // 18.9 MB
    __hip_bfloat16* val = (__hip_bfloat16*)(xdef + (size_t)B_ * C_ * HW_);  // 85 MB
    unsigned short* wpack = (unsigned short*)(val + (size_t)CK_ * BHW_);    // 72 KB

    ln_kernel<<<(BHW_ + 255) / 256, 256, 0, stream>>>(x, lnw, lnb, xn);
    conv27_kernel<<<(3 * BHW_ + 255) / 256, 256, 0, stream>>>(
        xn, offw, offb, maskw, maskb, offset, mask);
    prepack_kernel<<<1, 256, 0, stream>>>(dw, wpack);
    gather_kernel<<<(KK_ * BHW_ + 255) / 256, 256, 0, stream>>>(
        xn, offset, mask, val);
    contract_mfma<<<BHW_ / 64, 256, 0, stream>>>(
        (const unsigned short*)val, wpack, db, (float*)xdef);
    fuse_kernel<<<(2 * BHW_ + 255) / 256, 256, 0, stream>>>(
        xdef, fw, fb, premask, x, out);
}

// Round 5
// 211.254 us; speedup vs baseline: 13.5941x; 1.9255x over previous
//
#include <hip/hip_runtime.h>
#include <hip/hip_bf16.h>
#include <math.h>

#define B_ 2
#define C_ 64
#define H_ 192
#define W_ 192
#define HW_ (H_*W_)
#define BHW_ (B_*HW_)
#define KK_ 9
#define CK_ (C_*KK_)      // 576
#define KSTEPS_ (CK_/32)  // 18

typedef __bf16 bf16x8 __attribute__((ext_vector_type(8)));
typedef float  f32x4  __attribute__((ext_vector_type(4)));

// ---------------- LayerNorm over channel axis (f32 + bf16 outputs) ----------
__global__ void ln_kernel(const float* __restrict__ x,
                          const float* __restrict__ lnw,
                          const float* __restrict__ lnb,
                          float* __restrict__ xn,
                          unsigned short* __restrict__ xnb) {
    int p = blockIdx.x * blockDim.x + threadIdx.x;
    if (p >= BHW_) return;
    int b = p / HW_, pix = p % HW_;
    const float* xb = x + (size_t)b * C_ * HW_ + pix;
    float v[C_];
    float s = 0.f, s2 = 0.f;
    #pragma unroll
    for (int c = 0; c < C_; ++c) {
        v[c] = xb[(size_t)c * HW_];
        s += v[c]; s2 += v[c] * v[c];
    }
    float mu  = s * (1.0f / C_);
    float var = s2 * (1.0f / C_) - mu * mu;
    float inv = rsqrtf(var + 1e-5f);
    float* yb = xn + (size_t)b * C_ * HW_ + pix;
    unsigned short* zb = xnb + (size_t)b * C_ * HW_ + pix;
    #pragma unroll
    for (int c = 0; c < C_; ++c) {
        float y = (v[c] - mu) * inv * lnw[c] + lnb[c];
        yb[(size_t)c * HW_] = y;
        __hip_bfloat16 hb = __float2bfloat16(y);
        zb[(size_t)c * HW_] = *reinterpret_cast<unsigned short*>(&hb);
    }
}

// ---------------- weight prepack (all three GEMMs) -------------------------
// wpack (deform): A[oc][ck], ck = c*9+k  (matches val layout [ck][p])
// wpf   (fusion): A[oc][ck], ck = k*64+c (tap-outer, for shifted-pixel B)
// wpc   (conv27): A[oc][ck], ck = k*64+c; oc 0..17 offw, 18..26 maskw, 27..31 zero
__global__ void prepack_kernel(const float* __restrict__ dw,
                               const float* __restrict__ fw,
                               const float* __restrict__ offw,
                               const float* __restrict__ maskw,
                               unsigned short* __restrict__ wpack,
                               unsigned short* __restrict__ wpf,
                               unsigned short* __restrict__ wpc) {
    const int n1 = 4 * KSTEPS_ * 64 * 8;   // 36864 (deform)
    const int n2 = 4 * KSTEPS_ * 64 * 8;   // 36864 (fusion)
    const int n3 = 2 * KSTEPS_ * 64 * 8;   // 18432 (conv27)
    int gid = blockIdx.x * blockDim.x + threadIdx.x;
    int nth = gridDim.x * blockDim.x;
    for (int idx = gid; idx < n1 + n2 + n3; idx += nth) {
        int which = (idx < n1) ? 0 : (idx < n1 + n2 ? 1 : 2);
        int rem = idx - (which == 0 ? 0 : (which == 1 ? n1 : n1 + n2));
        int j = rem & 7;
        int l = (rem >> 3) & 63;
        int rest = rem >> 9;
        int s = rest % KSTEPS_;
        int t = rest / KSTEPS_;
        int oc = t * 16 + (l & 15);
        int ck = s * 32 + (l >> 4) * 8 + j;
        float v;
        if (which == 0) {
            v = dw[(size_t)oc * CK_ + ck];                 // ck = c*9+k already
        } else {
            int k = ck >> 6, c = ck & 63;
            if (which == 1) {
                v = fw[(size_t)oc * CK_ + c * 9 + k];
            } else {
                v = (oc < 18) ? offw[(size_t)oc * CK_ + c * 9 + k]
                  : (oc < 27) ? maskw[(size_t)(oc - 18) * CK_ + c * 9 + k]
                  : 0.f;
            }
        }
        __hip_bfloat16 hb = __float2bfloat16(v);
        unsigned short u = *reinterpret_cast<unsigned short*>(&hb);
        if (which == 0) wpack[rem] = u;
        else if (which == 1) wpf[rem] = u;
        else wpc[rem] = u;
    }
}

// ---------------- conv27 via MFMA: offset(18) + mask(9) --------------------
// wave = 16 pixels x 32 oc (27 live); B from xnb at shifted pixel
__global__ void __launch_bounds__(256) conv27_mfma(
        const unsigned short* __restrict__ xnb,
        const unsigned short* __restrict__ wpc,
        const float* __restrict__ offb, const float* __restrict__ maskb,
        float* __restrict__ offset, float* __restrict__ mask) {
    int wave = threadIdx.x >> 6;
    int lane = threadIdx.x & 63;
    int ptile = blockIdx.x * 4 + wave;
    int p = ptile * 16 + (lane & 15);
    int kchunk = lane >> 4;
    int b = p / HW_, pix = p - b * HW_;
    int h = pix / W_, w = pix - h * W_;

    f32x4 acc[2];
    #pragma unroll
    for (int t = 0; t < 2; ++t) acc[t] = f32x4{0.f, 0.f, 0.f, 0.f};

    const unsigned short* xb = xnb + (size_t)b * C_ * HW_;
    #pragma unroll
    for (int s = 0; s < KSTEPS_; ++s) {
        const int k = s >> 1;
        const int dy = k / 3 - 1, dx = k % 3 - 1;
        bool ok = ((unsigned)(h + dy) < (unsigned)H_) &&
                  ((unsigned)(w + dx) < (unsigned)W_);
        int sp = ok ? (pix + dy * W_ + dx) : pix;
        int cbase = (s & 1) * 32 + kchunk * 8;
        const unsigned short* vs = xb + (size_t)cbase * HW_ + sp;
        union { unsigned short u[8]; bf16x8 v; } bu;
        #pragma unroll
        for (int j = 0; j < 8; ++j)
            bu.u[j] = ok ? vs[(size_t)j * HW_] : (unsigned short)0;
        #pragma unroll
        for (int t = 0; t < 2; ++t) {
            bf16x8 afrag = *reinterpret_cast<const bf16x8*>(
                wpc + ((size_t)(t * KSTEPS_ + s) * 64 + lane) * 8);
            acc[t] = __builtin_amdgcn_mfma_f32_16x16x32_bf16(afrag, bu.v, acc[t], 0, 0, 0);
        }
    }

    #pragma unroll
    for (int t = 0; t < 2; ++t) {
        #pragma unroll
        for (int r = 0; r < 4; ++r) {
            int oc = t * 16 + kchunk * 4 + r;
            if (oc < 18) {
                offset[((size_t)b * 18 + oc) * HW_ + pix] = acc[t][r] + offb[oc];
            } else if (oc < 27) {
                float a = acc[t][r] + maskb[oc - 18];
                mask[((size_t)b * 9 + (oc - 18)) * HW_ + pix] = 1.f / (1.f + expf(-a));
            }
        }
    }
}

// ---------------- D1: modulated bilinear gather -> im2col (bf16) -----------
__global__ void gather_kernel(const float* __restrict__ xn,
                              const float* __restrict__ offset,
                              const float* __restrict__ mask,
                              __hip_bfloat16* __restrict__ val) {
    int tid = blockIdx.x * blockDim.x + threadIdx.x;
    if (tid >= KK_ * BHW_) return;
    int kk = tid / BHW_;
    int p  = tid - kk * BHW_;
    kk = __builtin_amdgcn_readfirstlane(kk);
    int b = p / HW_, pix = p % HW_;
    int h = pix / W_, w = pix % W_;

    float dy = offset[((size_t)b * 18 + 2 * kk) * HW_ + pix];
    float dx = offset[((size_t)b * 18 + 2 * kk + 1) * HW_ + pix];
    float m  = mask[((size_t)b * 9 + kk) * HW_ + pix];

    float py = dy + (float)(h - 1 + kk / 3);
    float px = dx + (float)(w - 1 + kk % 3);
    float fy = floorf(py), fx = floorf(px);
    float ly = py - fy, lx = px - fx;
    int y0 = (int)fy, x0 = (int)fx;
    int y1 = y0 + 1, x1 = x0 + 1;
    bool oky0 = (unsigned)y0 < (unsigned)H_;
    bool oky1 = (unsigned)y1 < (unsigned)H_;
    bool okx0 = (unsigned)x0 < (unsigned)W_;
    bool okx1 = (unsigned)x1 < (unsigned)W_;
    int cy0 = min(max(y0, 0), H_ - 1), cy1 = min(max(y1, 0), H_ - 1);
    int cx0 = min(max(x0, 0), W_ - 1), cx1 = min(max(x1, 0), W_ - 1);
    int a00 = cy0 * W_ + cx0, a01 = cy0 * W_ + cx1;
    int a10 = cy1 * W_ + cx0, a11 = cy1 * W_ + cx1;
    float q00 = (oky0 && okx0) ? (1.f - ly) * (1.f - lx) * m : 0.f;
    float q01 = (oky0 && okx1) ? (1.f - ly) * lx * m : 0.f;
    float q10 = (oky1 && okx0) ? ly * (1.f - lx) * m : 0.f;
    float q11 = (oky1 && okx1) ? ly * lx * m : 0.f;

    const float* xb = xn + (size_t)b * C_ * HW_;
    __hip_bfloat16* vb = val + p;
    #pragma unroll 4
    for (int c = 0; c < C_; ++c) {
        const float* xc = xb + (size_t)c * HW_;
        float v = q00 * xc[a00] + q01 * xc[a01] + q10 * xc[a10] + q11 * xc[a11];
        vb[(size_t)(c * KK_ + kk) * BHW_] = __float2bfloat16(v);
    }
}

// ---------------- D2: MFMA contraction -> xdef (bf16) ----------------------
__global__ void __launch_bounds__(256) contract_mfma(
        const unsigned short* __restrict__ val,
        const unsigned short* __restrict__ wpack,
        const float* __restrict__ db,
        unsigned short* __restrict__ xdefb) {
    int wave = threadIdx.x >> 6;
    int lane = threadIdx.x & 63;
    int ptile = blockIdx.x * 4 + wave;
    int p = ptile * 16 + (lane & 15);
    int kchunk = lane >> 4;

    f32x4 acc[4];
    #pragma unroll
    for (int t = 0; t < 4; ++t) acc[t] = f32x4{0.f, 0.f, 0.f, 0.f};

    for (int s = 0; s < KSTEPS_; ++s) {
        union { unsigned short u[8]; bf16x8 v; } bu;
        const unsigned short* vs = val + ((size_t)s * 32 + kchunk * 8) * BHW_ + p;
        #pragma unroll
        for (int j = 0; j < 8; ++j) bu.u[j] = vs[(size_t)j * BHW_];
        #pragma unroll
        for (int t = 0; t < 4; ++t) {
            bf16x8 afrag = *reinterpret_cast<const bf16x8*>(
                wpack + ((size_t)(t * KSTEPS_ + s) * 64 + lane) * 8);
            acc[t] = __builtin_amdgcn_mfma_f32_16x16x32_bf16(afrag, bu.v, acc[t], 0, 0, 0);
        }
    }

    int b = p / HW_, pix = p % HW_;
    #pragma unroll
    for (int t = 0; t < 4; ++t) {
        #pragma unroll
        for (int r = 0; r < 4; ++r) {
            int oc = t * 16 + kchunk * 4 + r;
            __hip_bfloat16 hb = __float2bfloat16(acc[t][r] + db[oc]);
            xdefb[((size_t)b * C_ + oc) * HW_ + pix] =
                *reinterpret_cast<unsigned short*>(&hb);
        }
    }
}

// ---------------- fusion conv via MFMA + pre_mask blend --------------------
__global__ void __launch_bounds__(256) fuse_mfma(
        const unsigned short* __restrict__ xdefb,
        const unsigned short* __restrict__ wpf,
        const float* __restrict__ fb,
        const float* __restrict__ premask,
        const float* __restrict__ xin,
        float* __restrict__ out) {
    int wave = threadIdx.x >> 6;
    int lane = threadIdx.x & 63;
    int ptile = blockIdx.x * 4 + wave;
    int p = ptile * 16 + (lane & 15);
    int kchunk = lane >> 4;
    int b = p / HW_, pix = p - b * HW_;
    int h = pix / W_, w = pix - h * W_;

    f32x4 acc[4];
    #pragma unroll
    for (int t = 0; t < 4; ++t) acc[t] = f32x4{0.f, 0.f, 0.f, 0.f};

    const unsigned short* xb = xdefb + (size_t)b * C_ * HW_;
    #pragma unroll
    for (int s = 0; s < KSTEPS_; ++s) {
        const int k = s >> 1;
        const int dy = k / 3 - 1, dx = k % 3 - 1;
        bool ok = ((unsigned)(h + dy) < (unsigned)H_) &&
                  ((unsigned)(w + dx) < (unsigned)W_);
        int sp = ok ? (pix + dy * W_ + dx) : pix;
        int cbase = (s & 1) * 32 + kchunk * 8;
        const unsigned short* vs = xb + (size_t)cbase * HW_ + sp;
        union { unsigned short u[8]; bf16x8 v; } bu;
        #pragma unroll
        for (int j = 0; j < 8; ++j)
            bu.u[j] = ok ? vs[(size_t)j * HW_] : (unsigned short)0;
        #pragma unroll
        for (int t = 0; t < 4; ++t) {
            bf16x8 afrag = *reinterpret_cast<const bf16x8*>(
                wpf + ((size_t)(t * KSTEPS_ + s) * 64 + lane) * 8);
            acc[t] = __builtin_amdgcn_mfma_f32_16x16x32_bf16(afrag, bu.v, acc[t], 0, 0, 0);
        }
    }

    float pm = premask[(size_t)b * HW_ + pix];
    #pragma unroll
    for (int t = 0; t < 4; ++t) {
        #pragma unroll
        for (int r = 0; r < 4; ++r) {
            int oc = t * 16 + kchunk * 4 + r;
            size_t oidx = ((size_t)b * C_ + oc) * HW_ + pix;
            out[oidx] = (acc[t][r] + fb[oc]) * pm + xin[oidx] * (1.f - pm);
        }
    }
}

extern "C" void kernel_launch(void* const* d_in, const int* in_sizes, int n_in,
                              void* d_out, int out_size, void* d_ws, size_t ws_size,
                              hipStream_t stream) {
    const float* x       = (const float*)d_in[0];
    const float* premask = (const float*)d_in[1];
    const float* lnw     = (const float*)d_in[2];
    const float* lnb     = (const float*)d_in[3];
    const float* offw    = (const float*)d_in[4];
    const float* offb    = (const float*)d_in[5];
    const float* maskw   = (const float*)d_in[6];
    const float* maskb   = (const float*)d_in[7];
    const float* dw      = (const float*)d_in[8];
    const float* db      = (const float*)d_in[9];
    const float* fw      = (const float*)d_in[10];
    const float* fb      = (const float*)d_in[11];
    float* out = (float*)d_out;

    char* ws = (char*)d_ws;
    float* xn            = (float*)ws;                     ws += sizeof(float) * B_ * C_ * HW_;
    unsigned short* xnb  = (unsigned short*)ws;            ws += sizeof(short) * B_ * C_ * HW_;
    float* offset        = (float*)ws;                     ws += sizeof(float) * B_ * 18 * HW_;
    float* mask          = (float*)ws;                     ws += sizeof(float) * B_ * 9 * HW_;
    unsigned short* xdefb = (unsigned short*)ws;           ws += sizeof(short) * B_ * C_ * HW_;
    __hip_bfloat16* val  = (__hip_bfloat16*)ws;            ws += sizeof(short) * (size_t)CK_ * BHW_;
    unsigned short* wpack = (unsigned short*)ws;           ws += sizeof(short) * 4 * KSTEPS_ * 64 * 8;
    unsigned short* wpf   = (unsigned short*)ws;           ws += sizeof(short) * 4 * KSTEPS_ * 64 * 8;
    unsigned short* wpc   = (unsigned short*)ws;           ws += sizeof(short) * 2 * KSTEPS_ * 64 * 8;

    ln_kernel<<<(BHW_ + 255) / 256, 256, 0, stream>>>(x, lnw, lnb, xn, xnb);
    prepack_kernel<<<36, 256, 0, stream>>>(dw, fw, offw, maskw, wpack, wpf, wpc);
    conv27_mfma<<<BHW_ / 64, 256, 0, stream>>>(xnb, wpc, offb, maskb, offset, mask);
    gather_kernel<<<(KK_ * BHW_ + 255) / 256, 256, 0, stream>>>(
        xn, offset, mask, val);
    contract_mfma<<<BHW_ / 64, 256, 0, stream>>>(
        (const unsigned short*)val, wpack, db, xdefb);
    fuse_mfma<<<BHW_ / 64, 256, 0, stream>>>(
        xdefb, wpf, fb, premask, x, out);
}